// Round 2
// baseline (94.275 us; speedup 1.0000x reference)
//
#include <hip/hip_runtime.h>

#define HH 512
#define IND 13
#define NN 2048
#define RR 256
#define WDIM 7168      // (13+1)*512
#define W1DIM 6656     // 13*512
#define NBLK 512       // n per block (4 waves x 128 n, nt=8)
#define NT 8
#define NTHREADS 256
#define NEG_HALF_LOG_2PI (-0.91893853320467274f)

typedef __attribute__((ext_vector_type(8))) short short8;   // 8 bf16 (4 VGPRs) MFMA A/B frag
typedef __attribute__((ext_vector_type(4))) float f32x4;    // MFMA C/D frag
typedef __attribute__((ext_vector_type(2))) float f32x2;    // packed-math pair

// fp32 -> bf16 round-to-nearest-even (bit pattern) -- used for w1 (error-dominant term)
__device__ __forceinline__ short f2bf(float f) {
    unsigned u = __float_as_uint(f);
    u += 0x7fffu + ((u >> 16) & 1u);
    return (short)(u >> 16);
}

// R22 = NBLK=512 structural halving. R21 post-mortem: fusing xprep away
// changed NOTHING (91.3 -> 91.7) => the timed window is ~82.5 us of fixed
// 256MiB ws-poison fills (2x ~41 us) + a ~9 us kernel. Pipe model says the
// kernel is LDS-read-bound: 64 ds_read_b128/wave in the main loop, paid per
// block, 8 blocks per r => per-CU LDS ~26k cyc ~ 11 us (MFMA ~2, VALU ~3.4).
// This round: NBLK 256->512 (nt=8), grid (256,4)=1024 blocks, lb(256,4)
// -> 4 blocks/CU resident (LDS 18.4KB*4=74KB, VGPR<=128), total main-loop
// LDS reads and staging redundancy both HALVE. Predict dur 91.7 -> ~86-88.
// If unchanged again: kernel << fill floor -> harness roofline.
// Ledger: relu-split BANNED (R3/R4/R15); divergent partial short8 writes
// BANNED (R11/R12); 512-thread blocks avoided (R5 confound); 256 thr,
// branch-free builds, direct relu = proven-green.

__global__ __launch_bounds__(NTHREADS, 4)
void ffrelu_mfma_fused(const float* __restrict__ x,
                       const float* __restrict__ y,
                       const float* __restrict__ w,
                       float* __restrict__ out) {
    __shared__ short Als[HH * 16];   // 16384 B: w1 rows [w1(13)|0(3)]
    __shared__ float w2s[HH];        // 2048 B, fp32

    const int tid = threadIdx.x;
    const int r = blockIdx.x;       // fast dim: same-r blocks -> same XCD
    const int wave = tid >> 6;
    const int lane = tid & 63;
    const int m = lane & 15;        // MFMA row/col index within 16
    const int q = lane >> 4;        // quad 0..3

    const float* wr = w + (size_t)r * WDIM;

    // ---- stage w1 (bf16 RNE, 2 rows/thread, pads inline) + w2 ----
#pragma unroll
    for (int rr = 0; rr < 2; ++rr) {
        const int h = tid * 2 + rr;
        const float* p = wr + (size_t)h * IND;
        short tmp[16];
#pragma unroll
        for (int i = 0; i < 13; ++i) tmp[i] = f2bf(p[i]);
        tmp[13] = 0; tmp[14] = 0; tmp[15] = 0;
        *(short8*)&Als[h * 16]     = *(short8*)&tmp[0];
        *(short8*)&Als[h * 16 + 8] = *(short8*)&tmp[8];
    }
    w2s[tid]       = wr[W1DIM + tid];
    w2s[tid + 256] = wr[W1DIM + tid + 256];

    const bool lo  = (q >= 2);     // q2/q3 lanes carry x_lo
    const bool hi8 = (q & 1);      // q1/q3 lanes carry slice [8..12]
    const f32x2 zero2 = {0.0f, 0.0f};
    const f32x4 czero = {0.0f, 0.0f, 0.0f, 0.0f};   // loop-invariant C operand

    // ---- 8 B-frags (128 n per wave): in-kernel truncation-split build ----
    // Issued before the barrier: x-loads overlap the w staging latency.
    const int nb = blockIdx.y * NBLK + wave * (NT * 16);
    short8 bfrag[NT];
#pragma unroll
    for (int nt = 0; nt < NT; ++nt) {
        const float* xp = x + (size_t)(nb + nt * 16 + m) * IND;
        short hs[13], ls[13];
#pragma unroll
        for (int i = 0; i < 13; ++i) {
            float v = xp[i];
            unsigned u = __float_as_uint(v);
            hs[i] = (short)(u >> 16);                         // hi: truncate to bf16
            float res = v - __uint_as_float(u & 0xffff0000u); // exact remainder
            ls[i] = (short)(__float_as_uint(res) >> 16);      // lo: truncate remainder
        }
        short s[13];
#pragma unroll
        for (int i = 0; i < 13; ++i) s[i] = lo ? ls[i] : hs[i];
        short8 b;
        b[0] = hi8 ? s[8]     : s[0];
        b[1] = hi8 ? s[9]     : s[1];
        b[2] = hi8 ? s[10]    : s[2];
        b[3] = hi8 ? s[11]    : s[3];
        b[4] = hi8 ? s[12]    : s[4];
        b[5] = hi8 ? (short)0 : s[5];
        b[6] = hi8 ? (short)0 : s[6];
        b[7] = hi8 ? (short)0 : s[7];
        bfrag[nt] = b;
    }

    // prefetch epilogue operands (independent loads, hide under barrier wait)
    const float yv0 = y[nb + lane];
    const float yv1 = y[nb + 64 + lane];

    __syncthreads();

    // packed accumulators: muv[nt][0] covers regs {0,1}, muv[nt][1] regs {2,3}
    f32x2 muv[NT][2];
#pragma unroll
    for (int i = 0; i < NT; ++i) {
        muv[i][0] = zero2;
        muv[i][1] = zero2;
    }

    // ---- main loop: 32 h-tiles x 8 n-tiles; packed relu+dot ----
#pragma unroll 2
    for (int t = 0; t < 32; ++t) {
        const short8 a = *(const short8*)&Als[(t * 16 + m) * 16 + (q & 1) * 8];
        const f32x4 wv = *(const f32x4*)&w2s[t * 16 + q * 4];
        const f32x2 wv01 = {wv[0], wv[1]};
        const f32x2 wv23 = {wv[2], wv[3]};
#pragma unroll
        for (int nt = 0; nt < NT; ++nt) {
            f32x4 c = __builtin_amdgcn_mfma_f32_16x16x32_bf16(a, bfrag[nt], czero, 0, 0, 0);
            // C layout: col n = lane&15, row h = t*16 + q*4 + reg
            f32x2 c01 = {c[0], c[1]};
            f32x2 c23 = {c[2], c[3]};
            c01 = __builtin_elementwise_max(c01, zero2);
            c23 = __builtin_elementwise_max(c23, zero2);
            muv[nt][0] += c01 * wv01;    // v_pk_fma_f32
            muv[nt][1] += c23 * wv23;
        }
    }

    // ---- horizontal sum + quad butterfly ----
    float mu[NT];
#pragma unroll
    for (int nt = 0; nt < NT; ++nt) {
        f32x2 p = muv[nt][0] + muv[nt][1];
        float v = p[0] + p[1];
        v += __shfl_xor(v, 16, 64);
        v += __shfl_xor(v, 32, 64);
        mu[nt] = v;
    }

    // lane stores n = nb + lane (tiles 0..3) and n = nb + 64 + lane (tiles 4..7)
    float mu0, mu1;
    if (q == 0)      { mu0 = mu[0]; mu1 = mu[4]; }
    else if (q == 1) { mu0 = mu[1]; mu1 = mu[5]; }
    else if (q == 2) { mu0 = mu[2]; mu1 = mu[6]; }
    else             { mu0 = mu[3]; mu1 = mu[7]; }

    const int n0 = nb + lane;
    float resid0 = yv0 - mu0;
    float resid1 = yv1 - mu1;
    float* op = out + (size_t)r * NN;
    op[n0]      = fmaf(-0.5f * resid0, resid0, NEG_HALF_LOG_2PI);
    op[n0 + 64] = fmaf(-0.5f * resid1, resid1, NEG_HALF_LOG_2PI);
}

extern "C" void kernel_launch(void* const* d_in, const int* in_sizes, int n_in,
                              void* d_out, int out_size, void* d_ws, size_t ws_size,
                              hipStream_t stream) {
    const float* x = (const float*)d_in[0];   // [N, 13]
    const float* y = (const float*)d_in[1];   // [N, 1]
    const float* w = (const float*)d_in[2];   // [R, 7168]
    float* out = (float*)d_out;               // [R, N]
    (void)d_ws; (void)ws_size;                // ws deliberately untouched

    dim3 grid(RR, NN / NBLK);   // (256, 4): r fast -> same-r blocks share an XCD
    dim3 block(NTHREADS);
    ffrelu_mfma_fused<<<grid, block, 0, stream>>>(x, y, w, out);
}

// Round 3
// 94.216 us; speedup vs baseline: 1.0006x; 1.0006x over previous
//
#include <hip/hip_runtime.h>

#define HH 512
#define IND 13
#define NN 2048
#define RR 256
#define WDIM 7168      // (13+1)*512
#define W1DIM 6656     // 13*512
#define NBLK 512       // n per block (4 waves x 128 n, nt=8)
#define NT 8
#define NTHREADS 256
#define NEG_HALF_LOG_2PI (-0.91893853320467274f)

typedef __attribute__((ext_vector_type(8))) short short8;   // 8 bf16 (4 VGPRs) MFMA A/B frag
typedef __attribute__((ext_vector_type(4))) float f32x4;    // MFMA C/D frag
typedef __attribute__((ext_vector_type(2))) float f32x2;    // packed-math pair

// fp32 -> bf16 round-to-nearest-even (bit pattern) -- used for w1 (error-dominant term)
__device__ __forceinline__ short f2bf(float f) {
    unsigned u = __float_as_uint(f);
    u += 0x7fffu + ((u >> 16) & 1u);
    return (short)(u >> 16);
}

// R23 = single-variable spill retest. R22 (NT=8 + lb(,4)) REGRESSED
// (94.3 vs 91.7) despite halving per-CU DS traffic -> the DS-throughput
// model says it had to win, so the regression is the OTHER variable:
// lb(256,4) caps VGPR at 128; NT=8 live set (~bfrag32+muv32+misc+unroll2
// overlap+staging transients) peaks past 128 -> scratch spill. This round:
// identical kernel, lb(256,3) (cap ~168). If spill was the cause, kernel
// ~11.8 -> ~5.5-6.5 us, dur -> ~87-89. If unchanged/worse: NT=8 is dead
// (latency-bound at 16 waves/CU), revert to NT=4 next and attack the wv
// read via operand-swapped MFMA (scalar w2 ds_read_b32).
// Fixed context: timed window carries ~82.5 us of harness ws-poison fills
// (2 x 41 us, invariant R20-R22); kernel is the only lever.
// Ledger: relu-split BANNED (R3/R4/R15); divergent partial short8 writes
// BANNED (R11/R12); 512-thread blocks avoided (R5 confound); 256 thr,
// branch-free builds, direct relu = proven-green.

__global__ __launch_bounds__(NTHREADS, 3)
void ffrelu_mfma_fused(const float* __restrict__ x,
                       const float* __restrict__ y,
                       const float* __restrict__ w,
                       float* __restrict__ out) {
    __shared__ short Als[HH * 16];   // 16384 B: w1 rows [w1(13)|0(3)]
    __shared__ float w2s[HH];        // 2048 B, fp32

    const int tid = threadIdx.x;
    const int r = blockIdx.x;       // fast dim: same-r blocks -> same XCD
    const int wave = tid >> 6;
    const int lane = tid & 63;
    const int m = lane & 15;        // MFMA row/col index within 16
    const int q = lane >> 4;        // quad 0..3

    const float* wr = w + (size_t)r * WDIM;

    // ---- stage w1 (bf16 RNE, 2 rows/thread, pads inline) + w2 ----
#pragma unroll
    for (int rr = 0; rr < 2; ++rr) {
        const int h = tid * 2 + rr;
        const float* p = wr + (size_t)h * IND;
        short tmp[16];
#pragma unroll
        for (int i = 0; i < 13; ++i) tmp[i] = f2bf(p[i]);
        tmp[13] = 0; tmp[14] = 0; tmp[15] = 0;
        *(short8*)&Als[h * 16]     = *(short8*)&tmp[0];
        *(short8*)&Als[h * 16 + 8] = *(short8*)&tmp[8];
    }
    w2s[tid]       = wr[W1DIM + tid];
    w2s[tid + 256] = wr[W1DIM + tid + 256];

    const bool lo  = (q >= 2);     // q2/q3 lanes carry x_lo
    const bool hi8 = (q & 1);      // q1/q3 lanes carry slice [8..12]
    const f32x2 zero2 = {0.0f, 0.0f};
    const f32x4 czero = {0.0f, 0.0f, 0.0f, 0.0f};   // loop-invariant C operand

    // ---- 8 B-frags (128 n per wave): in-kernel truncation-split build ----
    // Issued before the barrier: x-loads overlap the w staging latency.
    const int nb = blockIdx.y * NBLK + wave * (NT * 16);
    short8 bfrag[NT];
#pragma unroll
    for (int nt = 0; nt < NT; ++nt) {
        const float* xp = x + (size_t)(nb + nt * 16 + m) * IND;
        short hs[13], ls[13];
#pragma unroll
        for (int i = 0; i < 13; ++i) {
            float v = xp[i];
            unsigned u = __float_as_uint(v);
            hs[i] = (short)(u >> 16);                         // hi: truncate to bf16
            float res = v - __uint_as_float(u & 0xffff0000u); // exact remainder
            ls[i] = (short)(__float_as_uint(res) >> 16);      // lo: truncate remainder
        }
        short s[13];
#pragma unroll
        for (int i = 0; i < 13; ++i) s[i] = lo ? ls[i] : hs[i];
        short8 b;
        b[0] = hi8 ? s[8]     : s[0];
        b[1] = hi8 ? s[9]     : s[1];
        b[2] = hi8 ? s[10]    : s[2];
        b[3] = hi8 ? s[11]    : s[3];
        b[4] = hi8 ? s[12]    : s[4];
        b[5] = hi8 ? (short)0 : s[5];
        b[6] = hi8 ? (short)0 : s[6];
        b[7] = hi8 ? (short)0 : s[7];
        bfrag[nt] = b;
    }

    // prefetch epilogue operands (independent loads, hide under barrier wait)
    const float yv0 = y[nb + lane];
    const float yv1 = y[nb + 64 + lane];

    __syncthreads();

    // packed accumulators: muv[nt][0] covers regs {0,1}, muv[nt][1] regs {2,3}
    f32x2 muv[NT][2];
#pragma unroll
    for (int i = 0; i < NT; ++i) {
        muv[i][0] = zero2;
        muv[i][1] = zero2;
    }

    // ---- main loop: 32 h-tiles x 8 n-tiles; packed relu+dot ----
#pragma unroll 2
    for (int t = 0; t < 32; ++t) {
        const short8 a = *(const short8*)&Als[(t * 16 + m) * 16 + (q & 1) * 8];
        const f32x4 wv = *(const f32x4*)&w2s[t * 16 + q * 4];
        const f32x2 wv01 = {wv[0], wv[1]};
        const f32x2 wv23 = {wv[2], wv[3]};
#pragma unroll
        for (int nt = 0; nt < NT; ++nt) {
            f32x4 c = __builtin_amdgcn_mfma_f32_16x16x32_bf16(a, bfrag[nt], czero, 0, 0, 0);
            // C layout: col n = lane&15, row h = t*16 + q*4 + reg
            f32x2 c01 = {c[0], c[1]};
            f32x2 c23 = {c[2], c[3]};
            c01 = __builtin_elementwise_max(c01, zero2);
            c23 = __builtin_elementwise_max(c23, zero2);
            muv[nt][0] += c01 * wv01;    // v_pk_fma_f32
            muv[nt][1] += c23 * wv23;
        }
    }

    // ---- horizontal sum + quad butterfly ----
    float mu[NT];
#pragma unroll
    for (int nt = 0; nt < NT; ++nt) {
        f32x2 p = muv[nt][0] + muv[nt][1];
        float v = p[0] + p[1];
        v += __shfl_xor(v, 16, 64);
        v += __shfl_xor(v, 32, 64);
        mu[nt] = v;
    }

    // lane stores n = nb + lane (tiles 0..3) and n = nb + 64 + lane (tiles 4..7)
    float mu0, mu1;
    if (q == 0)      { mu0 = mu[0]; mu1 = mu[4]; }
    else if (q == 1) { mu0 = mu[1]; mu1 = mu[5]; }
    else if (q == 2) { mu0 = mu[2]; mu1 = mu[6]; }
    else             { mu0 = mu[3]; mu1 = mu[7]; }

    const int n0 = nb + lane;
    float resid0 = yv0 - mu0;
    float resid1 = yv1 - mu1;
    float* op = out + (size_t)r * NN;
    op[n0]      = fmaf(-0.5f * resid0, resid0, NEG_HALF_LOG_2PI);
    op[n0 + 64] = fmaf(-0.5f * resid1, resid1, NEG_HALF_LOG_2PI);
}

extern "C" void kernel_launch(void* const* d_in, const int* in_sizes, int n_in,
                              void* d_out, int out_size, void* d_ws, size_t ws_size,
                              hipStream_t stream) {
    const float* x = (const float*)d_in[0];   // [N, 13]
    const float* y = (const float*)d_in[1];   // [N, 1]
    const float* w = (const float*)d_in[2];   // [R, 7168]
    float* out = (float*)d_out;               // [R, N]
    (void)d_ws; (void)ws_size;                // ws deliberately untouched

    dim3 grid(RR, NN / NBLK);   // (256, 4): r fast -> same-r blocks share an XCD
    dim3 block(NTHREADS);
    ffrelu_mfma_fused<<<grid, block, 0, stream>>>(x, y, w, out);
}

// Round 4
// 93.259 us; speedup vs baseline: 1.0109x; 1.0103x over previous
//
#include <hip/hip_runtime.h>

#define HH 512
#define IND 13
#define NN 2048
#define RR 256
#define WDIM 7168      // (13+1)*512
#define W1DIM 6656     // 13*512
#define NBLK 256       // n per block; each n covered by 2 waves (h-split pairs)
#define NT 8           // n-tiles per wave (128 n per wave)
#define NTHREADS 256
#define XPK_BYTES (NN * 32 * 2)   // 131072 B: packed x in d_ws
#define NEG_HALF_LOG_2PI (-0.91893853320467274f)

typedef __attribute__((ext_vector_type(8))) short short8;   // 8 bf16 (4 VGPRs) MFMA A/B frag
typedef __attribute__((ext_vector_type(4))) float f32x4;    // MFMA C/D frag
typedef __attribute__((ext_vector_type(2))) float f32x2;    // packed-math pair

// fp32 -> bf16 round-to-nearest-even (bit pattern) -- used for w1 (error-dominant term)
__device__ __forceinline__ short f2bf(float f) {
    unsigned u = __float_as_uint(f);
    u += 0x7fffu + ((u >> 16) & 1u);
    return (short)(u >> 16);
}

// R24 = h-split wave pairs on the proven R20 two-kernel base.
// R23 post-mortem: lb(,3) == lb(,4) at NT=8 (94.2 both) -> no spill; R22's
// regression re-attributed to the in-kernel NT=8 bfrag build (~1040 serial
// VALU cyc/wave pre-barrier, unhidden at 16 waves/CU). R21 vs R20 (+0.43 us
// for a 520-cyc build) corroborates. Fix: keep NT=8's DS amortization but
// (a) feed bfrag from the xprep prepack (build ~= 0, 8 VMEM b128 loads) and
// (b) keep 2048 blocks by splitting h across wave pairs: waves 0,1 do
// t=0..15, waves 2,3 do t=16..31, each covering 128 n. Per-wave main-loop
// ds_read_b128 64 -> 32; total DS halved at unchanged grid/staging/occupancy
// profile. Epilogue: butterfly as before + one LDS exchange (reuse dead Als)
// to sum h-halves; waves 2,3 retire early.
// Fixed context: ~82.5 us of harness ws-poison fills (2 x 41 us, invariant
// R20-R23); kernel residual is the only lever (NT=4 ~9 us, NT=8 ~11.8 us).
// Predict: kernel -> ~5.5-6.5 us, dur 94.2 -> ~87.5-89.5. Flat ~91 =>
// latency floor => roofline. >=94 => revert to R20 exactly.
// Ledger: relu-split BANNED (R3/R4/R15); divergent partial short8 writes
// BANNED (R11/R12); 512-thread blocks avoided (R5 confound); in-kernel NT=8
// build BANNED on hot path (R22/R23); 256 thr, branch-free builds, direct
// relu = proven-green.

__global__ __launch_bounds__(NTHREADS)
void xprep_kernel(const float* __restrict__ x, short* __restrict__ xpk) {
    const int n = blockIdx.x * NTHREADS + threadIdx.x;   // grid covers 2048 rows
    const float* xp = x + (size_t)n * IND;
    short tmp[32];
#pragma unroll
    for (int i = 0; i < 13; ++i) {
        float v = xp[i];
        unsigned u = __float_as_uint(v);
        tmp[i] = (short)(u >> 16);                         // hi: truncate to bf16
        float res = v - __uint_as_float(u & 0xffff0000u);  // exact remainder
        tmp[16 + i] = (short)(__float_as_uint(res) >> 16); // lo: truncate remainder
    }
    tmp[13] = 0; tmp[14] = 0; tmp[15] = 0;
    tmp[29] = 0; tmp[30] = 0; tmp[31] = 0;
    short8* dst = (short8*)(xpk + (size_t)n * 32);
    dst[0] = *(short8*)&tmp[0];
    dst[1] = *(short8*)&tmp[8];
    dst[2] = *(short8*)&tmp[16];
    dst[3] = *(short8*)&tmp[24];
}

template <bool FROM_WS>
__global__ __launch_bounds__(NTHREADS, 4)
void ffrelu_mfma_kernel(const float* __restrict__ x,
                        const float* __restrict__ y,
                        const float* __restrict__ w,
                        const short* __restrict__ xpk,
                        float* __restrict__ out) {
    __shared__ short Als[HH * 16];   // 16384 B: w1 rows [w1(13)|0(3)]
    __shared__ float w2s[HH];        // 2048 B, fp32

    const int tid = threadIdx.x;
    const int r = blockIdx.x;       // fast dim: same-r blocks -> same XCD
    const int wave = tid >> 6;
    const int lane = tid & 63;
    const int m = lane & 15;        // MFMA row/col index within 16
    const int q = lane >> 4;        // quad 0..3
    const int hseg = wave >> 1;     // 0: t=0..15, 1: t=16..31
    const int npart = wave & 1;     // which 128-n half of the block

    const float* wr = w + (size_t)r * WDIM;

    // ---- stage w1 (bf16 RNE, 2 rows/thread, pads inline) + w2; ONE barrier ----
#pragma unroll
    for (int rr = 0; rr < 2; ++rr) {
        const int h = tid * 2 + rr;
        const float* p = wr + (size_t)h * IND;
        short tmp[16];
#pragma unroll
        for (int i = 0; i < 13; ++i) tmp[i] = f2bf(p[i]);
        tmp[13] = 0; tmp[14] = 0; tmp[15] = 0;
        *(short8*)&Als[h * 16]     = *(short8*)&tmp[0];
        *(short8*)&Als[h * 16 + 8] = *(short8*)&tmp[8];
    }
    w2s[tid]       = wr[W1DIM + tid];
    w2s[tid + 256] = wr[W1DIM + tid + 256];

    const bool lo  = (q >= 2);     // q2/q3 lanes carry x_lo
    const bool hi8 = (q & 1);      // q1/q3 lanes carry slice [8..12]
    const f32x2 zero2 = {0.0f, 0.0f};
    const f32x4 czero = {0.0f, 0.0f, 0.0f, 0.0f};   // loop-invariant C operand

    // ---- 8 B-frags (128 n per wave) ----
    const int nb = blockIdx.y * NBLK + npart * 128;
    short8 bfrag[NT];
    if (FROM_WS) {
        // one aligned 16B load per frag: row nb+nt*16+m, half by lo, slice by hi8
        const short* base = xpk + (size_t)(nb + m) * 32 + (lo ? 16 : 0) + (hi8 ? 8 : 0);
#pragma unroll
        for (int nt = 0; nt < NT; ++nt) {
            bfrag[nt] = *(const short8*)(base + nt * 16 * 32);
        }
    } else {
        // fallback: in-kernel truncation build (branch-free) -- correctness path
#pragma unroll
        for (int nt = 0; nt < NT; ++nt) {
            const float* xp = x + (size_t)(nb + nt * 16 + m) * IND;
            short hs[13], ls[13];
#pragma unroll
            for (int i = 0; i < 13; ++i) {
                float v = xp[i];
                unsigned u = __float_as_uint(v);
                hs[i] = (short)(u >> 16);
                float res = v - __uint_as_float(u & 0xffff0000u);
                ls[i] = (short)(__float_as_uint(res) >> 16);
            }
            short s[13];
#pragma unroll
            for (int i = 0; i < 13; ++i) s[i] = lo ? ls[i] : hs[i];
            short8 b;
            b[0] = hi8 ? s[8]     : s[0];
            b[1] = hi8 ? s[9]     : s[1];
            b[2] = hi8 ? s[10]    : s[2];
            b[3] = hi8 ? s[11]    : s[3];
            b[4] = hi8 ? s[12]    : s[4];
            b[5] = hi8 ? (short)0 : s[5];
            b[6] = hi8 ? (short)0 : s[6];
            b[7] = hi8 ? (short)0 : s[7];
            bfrag[nt] = b;
        }
    }

    // prefetch epilogue operands (independent loads, hide under barrier wait)
    const float yv0 = y[nb + lane];
    const float yv1 = y[nb + 64 + lane];

    __syncthreads();

    // packed accumulators: muv[nt][0] covers regs {0,1}, muv[nt][1] regs {2,3}
    f32x2 muv[NT][2];
#pragma unroll
    for (int i = 0; i < NT; ++i) {
        muv[i][0] = zero2;
        muv[i][1] = zero2;
    }

    // ---- main loop: 16 h-tiles (this wave's half) x 8 n-tiles ----
    const int tbase = hseg * 16;
#pragma unroll 2
    for (int t = 0; t < 16; ++t) {
        const int tg = tbase + t;
        const short8 a = *(const short8*)&Als[(tg * 16 + m) * 16 + (q & 1) * 8];
        const f32x4 wv = *(const f32x4*)&w2s[tg * 16 + q * 4];
        const f32x2 wv01 = {wv[0], wv[1]};
        const f32x2 wv23 = {wv[2], wv[3]};
#pragma unroll
        for (int nt = 0; nt < NT; ++nt) {
            f32x4 c = __builtin_amdgcn_mfma_f32_16x16x32_bf16(a, bfrag[nt], czero, 0, 0, 0);
            // C layout: col n = lane&15, row h = tg*16 + q*4 + reg
            f32x2 c01 = {c[0], c[1]};
            f32x2 c23 = {c[2], c[3]};
            c01 = __builtin_elementwise_max(c01, zero2);
            c23 = __builtin_elementwise_max(c23, zero2);
            muv[nt][0] += c01 * wv01;    // v_pk_fma_f32
            muv[nt][1] += c23 * wv23;
        }
    }

    // ---- horizontal sum + quad butterfly (partial over this wave's h-half) ----
    float mu[NT];
#pragma unroll
    for (int nt = 0; nt < NT; ++nt) {
        f32x2 p = muv[nt][0] + muv[nt][1];
        float v = p[0] + p[1];
        v += __shfl_xor(v, 16, 64);
        v += __shfl_xor(v, 32, 64);
        mu[nt] = v;
    }

    // lane's n0 = nb + lane (tile q), n1 = nb + 64 + lane (tile 4+q)
    float mu0, mu1;
    if (q == 0)      { mu0 = mu[0]; mu1 = mu[4]; }
    else if (q == 1) { mu0 = mu[1]; mu1 = mu[5]; }
    else if (q == 2) { mu0 = mu[2]; mu1 = mu[6]; }
    else             { mu0 = mu[3]; mu1 = mu[7]; }

    // ---- cross-pair h-sum via LDS (reuse dead Als) ----
    float* mubuf = (float*)Als;            // 512 floats used of 16 KB
    __syncthreads();                       // all waves done reading Als
    if (hseg == 1) {
        mubuf[npart * 128 + lane]       = mu0;
        mubuf[256 + npart * 128 + lane] = mu1;
    }
    __syncthreads();
    if (hseg == 0) {
        mu0 += mubuf[npart * 128 + lane];
        mu1 += mubuf[256 + npart * 128 + lane];
        const int n0 = nb + lane;
        float resid0 = yv0 - mu0;
        float resid1 = yv1 - mu1;
        float* op = out + (size_t)r * NN;
        op[n0]      = fmaf(-0.5f * resid0, resid0, NEG_HALF_LOG_2PI);
        op[n0 + 64] = fmaf(-0.5f * resid1, resid1, NEG_HALF_LOG_2PI);
    }
    // waves 2,3 retire early, freeing SIMD slots for the next block
}

extern "C" void kernel_launch(void* const* d_in, const int* in_sizes, int n_in,
                              void* d_out, int out_size, void* d_ws, size_t ws_size,
                              hipStream_t stream) {
    const float* x = (const float*)d_in[0];   // [N, 13]
    const float* y = (const float*)d_in[1];   // [N, 1]
    const float* w = (const float*)d_in[2];   // [R, 7168]
    float* out = (float*)d_out;               // [R, N]
    short* xpk = (short*)d_ws;                // [N, 32] packed bf16 hi/lo

    dim3 grid(RR, NN / NBLK);   // (256, 8): r fast -> same-r blocks share an XCD
    dim3 block(NTHREADS);

    if (ws_size >= (size_t)XPK_BYTES) {
        xprep_kernel<<<NN / NTHREADS, NTHREADS, 0, stream>>>(x, xpk);
        ffrelu_mfma_kernel<true><<<grid, block, 0, stream>>>(x, y, w, xpk, out);
    } else {
        ffrelu_mfma_kernel<false><<<grid, block, 0, stream>>>(x, y, w, xpk, out);
    }
}

// Round 5
// 91.650 us; speedup vs baseline: 1.0286x; 1.0176x over previous
//
#include <hip/hip_runtime.h>

#define HH 512
#define IND 13
#define NN 2048
#define RR 256
#define WDIM 7168      // (13+1)*512
#define W1DIM 6656     // 13*512
#define NBLK 256       // n per block (4 waves x 64 n, nt=4)
#define NT 4
#define NTHREADS 256
#define NEG_HALF_LOG_2PI (-0.91893853320467274f)

// ws layout: [xpk 131072 B][w1pk 4194304 B][w2pk 524288 B]
#define XPK_BYTES   (NN * 32 * 2)                 // 131072
#define W1PK_OFF    XPK_BYTES
#define W1PK_BYTES  (RR * HH * 16 * 2)            // 4 MB, Als-linear per r
#define W2PK_OFF    (W1PK_OFF + W1PK_BYTES)       // 4325376
#define W2PK_BYTES  (RR * HH * 4)                 // 512 KB
#define WS_NEEDED   (W2PK_OFF + W2PK_BYTES)

typedef __attribute__((ext_vector_type(8))) short short8;   // 8 bf16 (4 VGPRs) MFMA A/B frag
typedef __attribute__((ext_vector_type(4))) float f32x4;    // MFMA C/D frag
typedef __attribute__((ext_vector_type(2))) float f32x2;    // packed-math pair

// fp32 -> bf16 round-to-nearest-even (bit pattern) -- used for w1 (error-dominant term)
__device__ __forceinline__ short f2bf(float f) {
    unsigned u = __float_as_uint(f);
    u += 0x7fffu + ((u >> 16) & 1u);
    return (short)(u >> 16);
}

// async global->LDS, 16 B per lane; LDS dest is wave-uniform base + lane*16
#define GLDS16(gsrc, ldst) \
    __builtin_amdgcn_global_load_lds( \
        (const __attribute__((address_space(1))) void*)(gsrc), \
        (__attribute__((address_space(3))) void*)(ldst), 16, 0, 0)

// R25 = staging ablation on the untouched R20 skeleton (91.27 best).
// R24 post-mortem: halving main-loop DS at unchanged grid was +2.0 us vs
// R20 -> DS-throughput theory falsified 3x (R22/R23/R24). Residual tracks
// per-block pre-barrier serial work instead. The never-ablated term is the
// w-staging block: ~26 global loads + ~80 f2bf VALU + 5 ds_writes, serial
// before the barrier, x2048 blocks (8x redundant per r) ~= 2-3 us/CU.
// This round: prep kernel (520 blocks) packs w1 (bf16, Als-linear) + w2
// (fp32) + x (hi/lo) into ws ONCE; main kernel stages Als/w2s via 4-5
// async global_load_lds(16B) issues per wave (zero VALU, zero VGPR
// round-trip, linear dest = prepack layout per m104 caveat). Main loop /
// grid / NT=4 / lb(256,3) / epilogue byte-identical to R20.
// Fixed context: ~82.5 us unconditional harness ws-poison fills (2x41,
// invariant R20-R24). Predict: residual 8.8 -> ~6.5-7.5, dur -> 89.5-90.5.
// Flat ~91 => kernel at launch+latency floor => declare roofline next.
// Ledger: relu-split BANNED (R3/R4/R15); divergent partial short8 writes
// BANNED (R11/R12); 512-thread blocks avoided (R5); in-kernel NT=8 build
// BANNED (R22/R23); h-split wave pairs BANNED (R24); NT=8 anywhere is
// net-negative; 256 thr, branch-free, direct relu = proven-green.

__global__ __launch_bounds__(NTHREADS)
void prep_kernel(const float* __restrict__ x, const float* __restrict__ w,
                 short* __restrict__ xpk, short* __restrict__ w1pk,
                 float* __restrict__ w2pk) {
    const int b = blockIdx.x;
    const int tid = threadIdx.x;
    if (b < 512) {
        // ---- w pack: one (r,h) row per thread ----
        const int gid = b * NTHREADS + tid;          // [0, 131072)
        const int r = gid >> 9;
        const int h = gid & 511;
        const float* p = w + (size_t)r * WDIM + (size_t)h * IND;
        short tmp[16];
#pragma unroll
        for (int i = 0; i < 13; ++i) tmp[i] = f2bf(p[i]);
        tmp[13] = 0; tmp[14] = 0; tmp[15] = 0;
        short8* dst = (short8*)(w1pk + (size_t)gid * 16);
        dst[0] = *(short8*)&tmp[0];
        dst[1] = *(short8*)&tmp[8];
        w2pk[gid] = w[(size_t)r * WDIM + W1DIM + h];
    } else {
        // ---- x pack: hi/lo truncation split, one n-row per thread ----
        const int n = (b - 512) * NTHREADS + tid;    // [0, 2048)
        const float* xp = x + (size_t)n * IND;
        short tmp[32];
#pragma unroll
        for (int i = 0; i < 13; ++i) {
            float v = xp[i];
            unsigned u = __float_as_uint(v);
            tmp[i] = (short)(u >> 16);                         // hi: truncate to bf16
            float res = v - __uint_as_float(u & 0xffff0000u);  // exact remainder
            tmp[16 + i] = (short)(__float_as_uint(res) >> 16); // lo: truncate remainder
        }
        tmp[13] = 0; tmp[14] = 0; tmp[15] = 0;
        tmp[29] = 0; tmp[30] = 0; tmp[31] = 0;
        short8* dst = (short8*)(xpk + (size_t)n * 32);
        dst[0] = *(short8*)&tmp[0];
        dst[1] = *(short8*)&tmp[8];
        dst[2] = *(short8*)&tmp[16];
        dst[3] = *(short8*)&tmp[24];
    }
}

template <bool FROM_WS>
__global__ __launch_bounds__(NTHREADS, 3)
void ffrelu_mfma_kernel(const float* __restrict__ x,
                        const float* __restrict__ y,
                        const float* __restrict__ w,
                        const short* __restrict__ xpk,
                        const short* __restrict__ w1pk,
                        const float* __restrict__ w2pk,
                        float* __restrict__ out) {
    __shared__ short Als[HH * 16];   // 16384 B: w1 rows [w1(13)|0(3)]
    __shared__ float w2s[HH];        // 2048 B, fp32

    const int tid = threadIdx.x;
    const int r = blockIdx.x;       // fast dim: same-r blocks -> same XCD
    const int wave = tid >> 6;
    const int lane = tid & 63;
    const int m = lane & 15;        // MFMA row/col index within 16
    const int q = lane >> 4;        // quad 0..3

    if (FROM_WS) {
        // ---- async staging from prepack: linear LDS dest, per-lane src ----
        // Als 16 KB: each wave covers 4 KB as 4 x (64 lanes x 16 B) issues.
        const char* w1g = (const char*)(w1pk + (size_t)r * (HH * 16))
                          + wave * 4096 + (size_t)lane * 16;
        char* alsb = (char*)Als + wave * 4096;
#pragma unroll
        for (int i = 0; i < 4; ++i) GLDS16(w1g + i * 1024, alsb + i * 1024);
        // w2s 2 KB: waves 0,1 one issue each (wave-uniform branch)
        if (wave < 2) {
            const char* w2g = (const char*)(w2pk + (size_t)r * HH)
                              + wave * 1024 + (size_t)lane * 16;
            GLDS16(w2g, (char*)w2s + wave * 1024);
        }
    } else {
        // ---- fallback: original in-kernel f2bf staging from w ----
        const float* wr = w + (size_t)r * WDIM;
#pragma unroll
        for (int rr = 0; rr < 2; ++rr) {
            const int h = tid * 2 + rr;
            const float* p = wr + (size_t)h * IND;
            short tmp[16];
#pragma unroll
            for (int i = 0; i < 13; ++i) tmp[i] = f2bf(p[i]);
            tmp[13] = 0; tmp[14] = 0; tmp[15] = 0;
            *(short8*)&Als[h * 16]     = *(short8*)&tmp[0];
            *(short8*)&Als[h * 16 + 8] = *(short8*)&tmp[8];
        }
        w2s[tid]       = wr[W1DIM + tid];
        w2s[tid + 256] = wr[W1DIM + tid + 256];
    }

    const bool lo  = (q >= 2);     // q2/q3 lanes carry x_lo
    const bool hi8 = (q & 1);      // q1/q3 lanes carry slice [8..12]
    const f32x2 zero2 = {0.0f, 0.0f};
    const f32x4 czero = {0.0f, 0.0f, 0.0f, 0.0f};   // loop-invariant C operand

    // ---- 4 B-frags (64 n per wave) ----
    const int nb = blockIdx.y * NBLK + wave * 64;
    short8 bfrag[NT];
    if (FROM_WS) {
        // one aligned 16B load per frag: row nb+nt*16+m, half by lo, slice by hi8
        const short* base = xpk + (size_t)(nb + m) * 32 + (lo ? 16 : 0) + (hi8 ? 8 : 0);
#pragma unroll
        for (int nt = 0; nt < NT; ++nt) {
            bfrag[nt] = *(const short8*)(base + nt * 16 * 32);
        }
    } else {
        // fallback: in-kernel truncation build (branch-free)
#pragma unroll
        for (int nt = 0; nt < NT; ++nt) {
            const float* xp = x + (size_t)(nb + nt * 16 + m) * IND;
            short hs[13], ls[13];
#pragma unroll
            for (int i = 0; i < 13; ++i) {
                float v = xp[i];
                unsigned u = __float_as_uint(v);
                hs[i] = (short)(u >> 16);
                float res = v - __uint_as_float(u & 0xffff0000u);
                ls[i] = (short)(__float_as_uint(res) >> 16);
            }
            short s[13];
#pragma unroll
            for (int i = 0; i < 13; ++i) s[i] = lo ? ls[i] : hs[i];
            short8 b;
            b[0] = hi8 ? s[8]     : s[0];
            b[1] = hi8 ? s[9]     : s[1];
            b[2] = hi8 ? s[10]    : s[2];
            b[3] = hi8 ? s[11]    : s[3];
            b[4] = hi8 ? s[12]    : s[4];
            b[5] = hi8 ? (short)0 : s[5];
            b[6] = hi8 ? (short)0 : s[6];
            b[7] = hi8 ? (short)0 : s[7];
            bfrag[nt] = b;
        }
    }

    // prefetch epilogue operand (independent load, hides under barrier wait)
    const float yv = y[nb + lane];

    __syncthreads();   // drains vmcnt (global_load_lds + bfrag) + lgkmcnt

    // packed accumulators: muv[nt][0] covers regs {0,1}, muv[nt][1] regs {2,3}
    f32x2 muv[NT][2];
#pragma unroll
    for (int i = 0; i < NT; ++i) {
        muv[i][0] = zero2;
        muv[i][1] = zero2;
    }

    // ---- main loop: 32 h-tiles x 4 n-tiles; packed relu+dot ----
#pragma unroll 2
    for (int t = 0; t < 32; ++t) {
        const short8 a = *(const short8*)&Als[(t * 16 + m) * 16 + (q & 1) * 8];
        const f32x4 wv = *(const f32x4*)&w2s[t * 16 + q * 4];
        const f32x2 wv01 = {wv[0], wv[1]};
        const f32x2 wv23 = {wv[2], wv[3]};
#pragma unroll
        for (int nt = 0; nt < NT; ++nt) {
            f32x4 c = __builtin_amdgcn_mfma_f32_16x16x32_bf16(a, bfrag[nt], czero, 0, 0, 0);
            // C layout: col n = lane&15, row h = t*16 + q*4 + reg
            f32x2 c01 = {c[0], c[1]};
            f32x2 c23 = {c[2], c[3]};
            c01 = __builtin_elementwise_max(c01, zero2);
            c23 = __builtin_elementwise_max(c23, zero2);
            muv[nt][0] += c01 * wv01;    // v_pk_fma_f32
            muv[nt][1] += c23 * wv23;
        }
    }

    // ---- horizontal sum + quad butterfly ----
    float mu[NT];
#pragma unroll
    for (int nt = 0; nt < NT; ++nt) {
        f32x2 p = muv[nt][0] + muv[nt][1];
        float v = p[0] + p[1];
        v += __shfl_xor(v, 16, 64);
        v += __shfl_xor(v, 32, 64);
        mu[nt] = v;
    }

    // lane stores n = nb + lane = nb + q*16 + m -> tile nt=q, col m
    float mu0;
    if (q == 0)      mu0 = mu[0];
    else if (q == 1) mu0 = mu[1];
    else if (q == 2) mu0 = mu[2];
    else             mu0 = mu[3];

    const int n0 = nb + lane;
    float resid0 = yv - mu0;
    out[(size_t)r * NN + n0] = fmaf(-0.5f * resid0, resid0, NEG_HALF_LOG_2PI);
}

extern "C" void kernel_launch(void* const* d_in, const int* in_sizes, int n_in,
                              void* d_out, int out_size, void* d_ws, size_t ws_size,
                              hipStream_t stream) {
    const float* x = (const float*)d_in[0];   // [N, 13]
    const float* y = (const float*)d_in[1];   // [N, 1]
    const float* w = (const float*)d_in[2];   // [R, 7168]
    float* out = (float*)d_out;               // [R, N]
    char* ws = (char*)d_ws;
    short* xpk  = (short*)ws;                 // [N, 32] packed bf16 hi/lo
    short* w1pk = (short*)(ws + W1PK_OFF);    // [R*H, 16] bf16, Als-linear
    float* w2pk = (float*)(ws + W2PK_OFF);    // [R, H] fp32

    dim3 grid(RR, NN / NBLK);   // (256, 8): r fast -> same-r blocks share an XCD
    dim3 block(NTHREADS);

    if (ws_size >= (size_t)WS_NEEDED) {
        prep_kernel<<<520, NTHREADS, 0, stream>>>(x, w, xpk, w1pk, w2pk);
        ffrelu_mfma_kernel<true><<<grid, block, 0, stream>>>(x, y, w, xpk, w1pk, w2pk, out);
    } else {
        ffrelu_mfma_kernel<false><<<grid, block, 0, stream>>>(x, y, w, xpk, w1pk, w2pk, out);
    }
}